// Round 11
// baseline (187.219 us; speedup 1.0000x reference)
//
#include <hip/hip_runtime.h>

// Problem constants (fixed by the reference): B=16 lists, N=1024, D=256.
#define BL 16
#define NL 1024
#define DD 256

typedef short bf16x8 __attribute__((ext_vector_type(8)));
typedef float f32x4 __attribute__((ext_vector_type(4)));

static __device__ __forceinline__ short f32_to_bf16(float f) {
  union { float f; unsigned u; } v; v.f = f;
  unsigned r = (v.u + 0x7FFFu + ((v.u >> 16) & 1u)) >> 16;  // RNE
  return (short)r;
}

// Async 16B global -> LDS. LDS dest must be wave-uniform base + lane*16
// (m104/m108). Global source address IS per-lane -> pre-swizzled source.
static __device__ __forceinline__ void g2l16(const short* g, short* l) {
  __builtin_amdgcn_global_load_lds(
      (const __attribute__((address_space(1))) void*)g,
      (__attribute__((address_space(3))) void*)l, 16, 0, 0);
}

// ---- Kernel 1: prep. Blocks [0,4096): X fp32->bf16. [4096,4608): W transpose.
__global__ __launch_bounds__(256) void k_prep(const float* __restrict__ X,
                                              const float* __restrict__ Wu,
                                              const float* __restrict__ Wl,
                                              short* __restrict__ Xb,
                                              short* __restrict__ WTu,
                                              short* __restrict__ WTl) {
  const int bid = blockIdx.x;
  if (bid < 4096) {
    int i = bid * 256 + threadIdx.x;  // float4 groups over 16384*256 floats
    const float4 v = ((const float4*)X)[i];
    short4 o;
    o.x = f32_to_bf16(v.x); o.y = f32_to_bf16(v.y);
    o.z = f32_to_bf16(v.z); o.w = f32_to_bf16(v.w);
    ((short4*)Xb)[i] = o;
  } else {
    const int id = bid - 4096;           // [0,512)
    const int z = id >> 8, d = id & 255; // matrix, source row of W
    const float* W = z ? Wl : Wu;
    short* WT = z ? WTl : WTu;
    const int e = threadIdx.x;
    WT[e * DD + d] = f32_to_bf16(W[d * DD + e]);  // WT[e][d] = W[d][e]
  }
}

// ---- Kernel 2: fused stage1+stage2.
// Block = (list b, 16-row p-strip pt in [0,64)). Grid 1024 x 256 thr (4 waves)
// = 4 blocks/CU, 16 waves/CU. LDS 24 KB. Per-block output region = 64 KB: the
// region size R5 MEASURED at 1.03x write amplification (66 MB) — vs 1.7-3.4x
// at 256 KB regions (R6/R9/R10). R5's latency problem (VGPR 52, serial loads)
// fixed here: wave owns 4 INDEPENDENT 16x64 q-tiles sharing one A-frag per ks
// -> 16 independent B loads + 16 MFMA per step; launch_bounds(256,4) -> 128
// VGPR cap. X staged once per strip (no q-halves) -> FETCH stays ~8 MB.
// bid = pt*16 + b -> XCD = b%8: 2 lists (1 MB X) pinned per XCD L2; the 4
// blocks co-resident on a CU share the same list's B panel.
__global__ __launch_bounds__(256, 4) void k_fused(const short* __restrict__ Xb,
                                                  const short* __restrict__ WTu,
                                                  const short* __restrict__ WTl,
                                                  const float* __restrict__ bu_p,
                                                  const float* __restrict__ bl_p,
                                                  float* __restrict__ out) {
  __shared__ short Asw[16 * 256];  // swizzled Xp strip, 8 KB
  __shared__ short Yu[16 * 256];   // swizzled Y_upper,  8 KB
  __shared__ short Yl[16 * 256];   // swizzled Y_lower,  8 KB

  const int bid = blockIdx.x;
  const int b = bid & 15, pt = bid >> 4;  // pt in [0,64): 16-row strip
  const int t = threadIdx.x, lane = t & 63, w = t >> 6;  // w in [0,4)
  const int r = lane & 15, quad = lane >> 4;
  const size_t listoff = (size_t)b * NL * DD;
  const short* Ap = Xb + listoff + (size_t)pt * 16 * DD;  // 16 x 256 bf16

  // ---- stage Xp into LDS, XOR-swizzled via pre-swizzled global source ----
  // 512 16B-chunks (32/row); read at (row*512+kb)^((row&7)<<4) -> src c^((c>>5)&7)
#pragma unroll
  for (int i = 0; i < 2; ++i) {
    const int c = i * 256 + t;  // per wave: uniform base + lane*16
    const int src = c ^ ((c >> 5) & 7);
    g2l16(Ap + src * 8, Asw + c * 8);
  }
  __syncthreads();

  // ---- phase 1: Y = Xp * W (both matrices); wave w -> cols [w*64,+64) ----
  {
    const int n0 = w * 64;
    f32x4 aU[4] = {}, aL[4] = {};
#pragma unroll
    for (int ks = 0; ks < 8; ++ks) {
      const int abyte = (r * 512 + ks * 64 + quad * 16) ^ ((r & 7) << 4);
      const bf16x8 af = *(const bf16x8*)((const char*)Asw + abyte);
#pragma unroll
      for (int nt = 0; nt < 4; ++nt) {
        const int off = (n0 + nt * 16 + r) * DD + ks * 32 + quad * 8;
        const bf16x8 bfu = *(const bf16x8*)(WTu + off);
        const bf16x8 bfl = *(const bf16x8*)(WTl + off);
        aU[nt] = __builtin_amdgcn_mfma_f32_16x16x32_bf16(af, bfu, aU[nt], 0, 0, 0);
        aL[nt] = __builtin_amdgcn_mfma_f32_16x16x32_bf16(af, bfl, aL[nt], 0, 0, 0);
      }
    }
    // write Y (bf16) into swizzled LDS: D[m][n]: row = quad*4+i, col = n0+nt*16+r
#pragma unroll
    for (int nt = 0; nt < 4; ++nt)
#pragma unroll
      for (int i = 0; i < 4; ++i) {
        const int row = quad * 4 + i;
        const int col = n0 + nt * 16 + r;
        const int byte = (row * 512 + col * 2) ^ ((row & 7) << 4);
        *(short*)((char*)Yu + byte) = f32_to_bf16(aU[nt][i]);
        *(short*)((char*)Yl + byte) = f32_to_bf16(aL[nt][i]);
      }
  }
  __syncthreads();  // Yu + Yl published; last barrier

  // ---- phase 2: wave w owns q-tiles {w, w+4, w+8, w+12}; shared A-frag ----
  const float ub = bu_p[0], lb = bl_p[0];
  float* Ob = out + (size_t)b * NL * NL;
  const short* Bl = Xb + listoff;
  const int dq = pt >> 2;  // 64-wide q-tile containing the diagonal
  const int p = pt * 16 + r;  // this lane's output row

  const short* Bg[4];
  bool up[4];
#pragma unroll
  for (int tl = 0; tl < 4; ++tl) {
    const int qt = w + tl * 4;
    Bg[tl] = Bl + (size_t)qt * 64 * DD;
    up[tl] = (qt >= dq);  // diag tile treated as Upper in the main pass
  }

  f32x4 acc[4][4] = {};  // [tl][nt]: D row <- q, col <- p (swapped operands)
#pragma unroll
  for (int ks = 0; ks < 8; ++ks) {
    const int abyte = (r * 512 + ks * 64 + quad * 16) ^ ((r & 7) << 4);
    const bf16x8 afU = *(const bf16x8*)((const char*)Yu + abyte);
    const bf16x8 afL = *(const bf16x8*)((const char*)Yl + abyte);
#pragma unroll
    for (int tl = 0; tl < 4; ++tl) {
      const bf16x8 af = up[tl] ? afU : afL;
#pragma unroll
      for (int nt = 0; nt < 4; ++nt) {
        const bf16x8 bf = *(const bf16x8*)(Bg[tl] + (size_t)(nt * 16 + r) * DD + ks * 32 + quad * 8);
        acc[tl][nt] = __builtin_amdgcn_mfma_f32_16x16x32_bf16(bf, af, acc[tl][nt], 0, 0, 0);
      }
    }
  }

  // stores: lane -> row p (fixed), 4 consecutive q per f32x4; 64 KB region.
  float* row = Ob + (size_t)p * NL;
#pragma unroll
  for (int tl = 0; tl < 4; ++tl) {
    const int q0 = (w + tl * 4) * 64;
    const float bias = up[tl] ? ub : lb;
#pragma unroll
    for (int nt = 0; nt < 4; ++nt) {
      f32x4 v;
#pragma unroll
      for (int i = 0; i < 4; ++i) v[i] = acc[tl][nt][i] + bias;
      *(f32x4*)(row + q0 + nt * 16 + quad * 4) = v;
    }
  }

  // ---- diag fixup: owning wave recomputes tile dq with Y_L (acc regs freed),
  // overwrites q<p (same lane wrote those addresses above -> ordered).
  if (w == (dq & 3)) {
    const short* Bgd = Bl + (size_t)dq * 64 * DD;
    const int q0 = dq * 64;
    f32x4 accD[4] = {};
#pragma unroll
    for (int ks = 0; ks < 8; ++ks) {
      const int abyte = (r * 512 + ks * 64 + quad * 16) ^ ((r & 7) << 4);
      const bf16x8 afL = *(const bf16x8*)((const char*)Yl + abyte);
#pragma unroll
      for (int nt = 0; nt < 4; ++nt) {
        const bf16x8 bf = *(const bf16x8*)(Bgd + (size_t)(nt * 16 + r) * DD + ks * 32 + quad * 8);
        accD[nt] = __builtin_amdgcn_mfma_f32_16x16x32_bf16(bf, afL, accD[nt], 0, 0, 0);
      }
    }
#pragma unroll
    for (int nt = 0; nt < 4; ++nt)
#pragma unroll
      for (int i = 0; i < 4; ++i) {
        const int q = q0 + nt * 16 + quad * 4 + i;
        if (q < p) row[q] = accD[nt][i] + lb;
      }
  }
}

extern "C" void kernel_launch(void* const* d_in, const int* in_sizes, int n_in,
                              void* d_out, int out_size, void* d_ws, size_t ws_size,
                              hipStream_t stream) {
  const float* feats = (const float*)d_in[0];   // [B*N, D] fp32
  const float* Wu    = (const float*)d_in[1];   // [1, D, D]
  const float* bu    = (const float*)d_in[2];   // [1]
  const float* Wl    = (const float*)d_in[3];   // [1, D, D]
  const float* bl    = (const float*)d_in[4];   // [1]
  float* out = (float*)d_out;                   // [B, N, N] fp32

  char* ws = (char*)d_ws;
  short* Xb  = (short*)(ws);                                   // 8 MB bf16 X
  short* WTu = (short*)(ws + (size_t)8 * 1024 * 1024);         // 128 KB
  short* WTl = (short*)(ws + (size_t)8 * 1024 * 1024 + DD * DD * 2);

  // Prep: X->bf16 (4096 blocks) + W transpose (512 blocks), one dispatch.
  k_prep<<<4096 + 512, 256, 0, stream>>>(feats, Wu, Wl, Xb, WTu, WTl);

  // Fused stage1+stage2: 1024 blocks (64 strips x 16 lists), 256 threads,
  // 24 KB LDS -> 4 blocks/CU. XCD = bid%8 = b%8.
  k_fused<<<1024, 256, 0, stream>>>(Xb, WTu, WTl, bu, bl, out);
}

// Round 12
// 115.655 us; speedup vs baseline: 1.6188x; 1.6188x over previous
//
#include <hip/hip_runtime.h>

// Problem constants (fixed by the reference): B=16 lists, N=1024, D=256.
#define BL 16
#define NL 1024
#define DD 256

typedef short bf16x8 __attribute__((ext_vector_type(8)));
typedef float f32x4 __attribute__((ext_vector_type(4)));

static __device__ __forceinline__ short f32_to_bf16(float f) {
  union { float f; unsigned u; } v; v.f = f;
  unsigned r = (v.u + 0x7FFFu + ((v.u >> 16) & 1u)) >> 16;  // RNE
  return (short)r;
}

// Async 16B global -> LDS (DMA queue: many outstanding, does NOT block the
// wave -- the fix for R6-R11's one-load-per-wave latency wall).
static __device__ __forceinline__ void g2l16(const short* g, short* l) {
  __builtin_amdgcn_global_load_lds(
      (const __attribute__((address_space(1))) void*)g,
      (__attribute__((address_space(3))) void*)l, 16, 0, 0);
}

// ---- Kernel 1: prep. Blocks [0,4096): X fp32->bf16. [4096,4608): W transpose.
__global__ __launch_bounds__(256) void k_prep(const float* __restrict__ X,
                                              const float* __restrict__ Wu,
                                              const float* __restrict__ Wl,
                                              short* __restrict__ Xb,
                                              short* __restrict__ WTu,
                                              short* __restrict__ WTl) {
  const int bid = blockIdx.x;
  if (bid < 4096) {
    int i = bid * 256 + threadIdx.x;  // float4 groups over 16384*256 floats
    const float4 v = ((const float4*)X)[i];
    short4 o;
    o.x = f32_to_bf16(v.x); o.y = f32_to_bf16(v.y);
    o.z = f32_to_bf16(v.z); o.w = f32_to_bf16(v.w);
    ((short4*)Xb)[i] = o;
  } else {
    const int id = bid - 4096;           // [0,512)
    const int z = id >> 8, d = id & 255; // matrix, source row of W
    const float* W = z ? Wl : Wu;
    short* WT = z ? WTl : WTu;
    const int e = threadIdx.x;
    WT[e * DD + d] = f32_to_bf16(W[d * DD + e]);  // WT[e][d] = W[d][e]
  }
}

// ---- Kernel 2: fused stage1+stage2, T3/T4 pipelined phase 2.
// Block = (list b, 64-row p-strip pt). 256 blocks x 1024 thr = 1 block/CU.
// LDS 128 KB: Yu 32K, Yl 32K, Bb0/Bb1 32K (chunk double buffer; Bb0 also
// hosts the Xp staging for phase 1).
// Phase 2: 16 q-chunks (64 rows x 256 K = 32 KB). Chunk c+1 staged via
// global_load_lds (async DMA) while all 16 waves compute chunk c from LDS.
// Counted s_waitcnt vmcnt(N) (3 steady, never 0 mid-loop) + raw s_barrier +
// sched_barrier(0) fencing. Wave (pg,qg) holds its Y fragments afU/afL[8]
// IN REGISTERS for the whole loop (A-side LDS traffic = 0); per chunk:
// 8 ds_read_b128 (bf) + 16 MFMA (U and L, bf shared) + 1 f32x4 store.
// bid = pt*16 + b -> XCD = b%8 (list L2 pinning, R6-proven).
__global__ __launch_bounds__(1024, 4) void k_fused(const short* __restrict__ Xb,
                                                   const short* __restrict__ WTu,
                                                   const short* __restrict__ WTl,
                                                   const float* __restrict__ bu_p,
                                                   const float* __restrict__ bl_p,
                                                   float* __restrict__ out) {
  __shared__ short Yu[64 * 256];   // swizzled Y_upper, 32 KB
  __shared__ short Yl[64 * 256];   // swizzled Y_lower, 32 KB
  __shared__ short Bb0[64 * 256];  // chunk buffer 0 (also Xp stage), 32 KB
  __shared__ short Bb1[64 * 256];  // chunk buffer 1, 32 KB

  const int bid = blockIdx.x;
  const int b = bid & 15, pt = bid >> 4;  // pt in [0,16): 64-row strip
  const int t = threadIdx.x, lane = t & 63, w = t >> 6;  // w in [0,16)
  const int r = lane & 15, quad = lane >> 4;
  const size_t listoff = (size_t)b * NL * DD;
  const short* Ap = Xb + listoff + (size_t)pt * 64 * DD;  // 64 x 256 bf16
  const float ub = bu_p[0], lb = bl_p[0];                 // early (drained below)

  // ---- stage Xp into Bb0, XOR-swizzled via pre-swizzled source ----
  // 2048 16B-chunks (32/row); read at (row*512+kb)^((row&7)<<4) -> src c^((c>>5)&7)
#pragma unroll
  for (int i = 0; i < 2; ++i) {
    const int c16 = i * 1024 + t;
    const int src = c16 ^ ((c16 >> 5) & 7);
    g2l16(Ap + src * 8, Bb0 + c16 * 8);
  }
  __syncthreads();  // full drain: clean vmcnt baseline

  // ---- phase 1: Y = Xp * W (both matrices); wave w -> cols [w*16,+16) ----
  {
    const int n0 = w * 16;
    f32x4 aU[4] = {}, aL[4] = {};
#pragma unroll
    for (int ks = 0; ks < 8; ++ks) {
      bf16x8 af[4];
#pragma unroll
      for (int mt = 0; mt < 4; ++mt) {
        const int row = mt * 16 + r;
        const int abyte = (row * 512 + ks * 64 + quad * 16) ^ ((row & 7) << 4);
        af[mt] = *(const bf16x8*)((const char*)Bb0 + abyte);
      }
      const int off = (n0 + r) * DD + ks * 32 + quad * 8;
      const bf16x8 bfu = *(const bf16x8*)(WTu + off);
      const bf16x8 bfl = *(const bf16x8*)(WTl + off);
#pragma unroll
      for (int mt = 0; mt < 4; ++mt) {
        aU[mt] = __builtin_amdgcn_mfma_f32_16x16x32_bf16(af[mt], bfu, aU[mt], 0, 0, 0);
        aL[mt] = __builtin_amdgcn_mfma_f32_16x16x32_bf16(af[mt], bfl, aL[mt], 0, 0, 0);
      }
    }
    // write Y (bf16) swizzled: row = mt*16+quad*4+i, col = n0+r
#pragma unroll
    for (int mt = 0; mt < 4; ++mt)
#pragma unroll
      for (int i = 0; i < 4; ++i) {
        const int row = mt * 16 + quad * 4 + i;
        const int byte = (row * 512 + (n0 + r) * 2) ^ ((row & 7) << 4);
        *(short*)((char*)Yu + byte) = f32_to_bf16(aU[mt][i]);
        *(short*)((char*)Yl + byte) = f32_to_bf16(aL[mt][i]);
      }
  }
  __syncthreads();  // Yu/Yl visible; Bb0 (Xp) reads done; vmcnt clean (W loads used)

  // ---- stage chunk 0 into Bb0 (async; overlaps af register loads) ----
  const short* Bl = Xb + listoff;
#pragma unroll
  for (int i = 0; i < 2; ++i) {
    const int c16 = i * 1024 + t;
    const int src = c16 ^ ((c16 >> 5) & 7);
    g2l16(Bl + src * 8, Bb0 + c16 * 8);
  }

  // ---- load this wave's Y fragments into registers (whole-loop reuse) ----
  const int pg = w >> 2, qg = w & 3;  // wave = (p-group, q-group), 4x4
  const int prow = pg * 16 + r;       // Y row for the af fragment
  bf16x8 afU[8], afL[8];
#pragma unroll
  for (int ks = 0; ks < 8; ++ks) {
    const int abyte = (prow * 512 + ks * 64 + quad * 16) ^ ((prow & 7) << 4);
    afU[ks] = *(const bf16x8*)((const char*)Yu + abyte);
    afL[ks] = *(const bf16x8*)((const char*)Yl + abyte);
  }

  // ---- phase 2: 16 chunks, counted-vmcnt double-buffer pipeline ----
  float* Ob = out + (size_t)b * NL * NL;
  const int p = pt * 64 + pg * 16 + r;    // this lane's output row
  const int qrow = qg * 16 + r;           // B row within chunk for bf
  float* const prowp = Ob + (size_t)p * NL;

#pragma unroll
  for (int c = 0; c < 16; ++c) {
    // 1. issue async stage of chunk c+1 into the other buffer
    if (c + 1 < 16) {
      const short* Bgn = Bl + (size_t)(c + 1) * 64 * DD;
      short* dst = ((c + 1) & 1) ? Bb1 : Bb0;
#pragma unroll
      for (int i = 0; i < 2; ++i) {
        const int c16 = i * 1024 + t;
        const int src = c16 ^ ((c16 >> 5) & 7);
        g2l16(Bgn + src * 8, dst + c16 * 8);
      }
    }
    // 2. counted wait: drain chunk c's 2 DMA loads, keep c+1's in flight.
    //    outstanding (FIFO): [store(c-2)?, stage(c)x2, store(c-1)?, stage(c+1)x2]
    if (c == 0)       asm volatile("s_waitcnt vmcnt(2)" ::: "memory");
    else if (c == 15) asm volatile("s_waitcnt vmcnt(1)" ::: "memory");
    else              asm volatile("s_waitcnt vmcnt(3)" ::: "memory");
    __builtin_amdgcn_sched_barrier(0);
    __builtin_amdgcn_s_barrier();      // chunk c visible to all waves
    __builtin_amdgcn_sched_barrier(0);

    // 3. compute chunk c: 8 x (1 ds_read_b128 + 2 MFMA), af from registers
    const short* Bc = (c & 1) ? Bb1 : Bb0;
    f32x4 accU = {}, accL = {};
#pragma unroll
    for (int ks = 0; ks < 8; ++ks) {
      const int bbyte = (qrow * 512 + ks * 64 + quad * 16) ^ ((qrow & 7) << 4);
      const bf16x8 bf = *(const bf16x8*)((const char*)Bc + bbyte);
      accU = __builtin_amdgcn_mfma_f32_16x16x32_bf16(bf, afU[ks], accU, 0, 0, 0);
      accL = __builtin_amdgcn_mfma_f32_16x16x32_bf16(bf, afL[ks], accL, 0, 0, 0);
    }
    // store: lane -> row p, 4 consecutive q (f32x4); U/L merge per chunk
    const int qb = c * 64 + qg * 16 + quad * 4;
    f32x4 v;
    if (c > pt) {
#pragma unroll
      for (int i = 0; i < 4; ++i) v[i] = accU[i] + ub;
    } else if (c < pt) {
#pragma unroll
      for (int i = 0; i < 4; ++i) v[i] = accL[i] + lb;
    } else {
#pragma unroll
      for (int i = 0; i < 4; ++i)
        v[i] = (qb + i >= p) ? accU[i] + ub : accL[i] + lb;
    }
    *(f32x4*)(prowp + qb) = v;

    // 4. done-barrier: all waves finished reading Bc before it is re-staged
    if (c + 1 < 16) {
      __builtin_amdgcn_sched_barrier(0);
      __builtin_amdgcn_s_barrier();
      __builtin_amdgcn_sched_barrier(0);
    }
  }
}

extern "C" void kernel_launch(void* const* d_in, const int* in_sizes, int n_in,
                              void* d_out, int out_size, void* d_ws, size_t ws_size,
                              hipStream_t stream) {
  const float* feats = (const float*)d_in[0];   // [B*N, D] fp32
  const float* Wu    = (const float*)d_in[1];   // [1, D, D]
  const float* bu    = (const float*)d_in[2];   // [1]
  const float* Wl    = (const float*)d_in[3];   // [1, D, D]
  const float* bl    = (const float*)d_in[4];   // [1]
  float* out = (float*)d_out;                   // [B, N, N] fp32

  char* ws = (char*)d_ws;
  short* Xb  = (short*)(ws);                                   // 8 MB bf16 X
  short* WTu = (short*)(ws + (size_t)8 * 1024 * 1024);         // 128 KB
  short* WTl = (short*)(ws + (size_t)8 * 1024 * 1024 + DD * DD * 2);

  // Prep: X->bf16 (4096 blocks) + W transpose (512 blocks), one dispatch.
  k_prep<<<4096 + 512, 256, 0, stream>>>(feats, Wu, Wl, Xb, WTu, WTl);

  // Fused stage1+stage2: 256 blocks (16 strips x 16 lists), 1024 threads,
  // 128 KB LDS -> 1 block/CU. XCD = bid%8 = b%8.
  k_fused<<<256, 1024, 0, stream>>>(Xb, WTu, WTl, bu, bl, out);
}